// Round 3
// baseline (3222.490 us; speedup 1.0000x reference)
//
#include <hip/hip_runtime.h>

#define NFEAT 512
#define HID 16

// ---------------- degree / norm ----------------
__global__ void k_deg_init(float* __restrict__ deg, int n) {
  int i = blockIdx.x * 256 + threadIdx.x;
  if (i < n) deg[i] = 1.0f;  // self loop
}

__global__ void k_deg_count(const int* __restrict__ ei, float* __restrict__ deg, int E) {
  int e = blockIdx.x * 256 + threadIdx.x;
  if (e < E) atomicAdd(&deg[ei[(size_t)E + e]], 1.0f);
}

__global__ void k_dinv(float* __restrict__ deg, int n) {
  int i = blockIdx.x * 256 + threadIdx.x;
  if (i < n) deg[i] = rsqrtf(deg[i]);  // in-place: deg -> dinv
}

// ---------------- GEMM1: h1 = x @ W1  (N x 512 @ 512 x 16) ----------------
// Block: 256 threads, 256 rows. W1 (32KB) fully in LDS; x staged in 16-wide
// k-chunks (single buffer, loads for next chunk issued before compute).
// Thread t: jq = t&3 (4 output cols), rg = t>>2; handles rows rg + 64m, m=0..3.
#define KC 16
#define NC (NFEAT / KC)
#define XPAD 20  // 16 + 4 pad: float4-aligned, spreads banks

__device__ __forceinline__ void fma4(float4& a, float s, const float4& b) {
  a.x += s * b.x;
  a.y += s * b.y;
  a.z += s * b.z;
  a.w += s * b.w;
}

__global__ __launch_bounds__(256) void k_gemm1(const float* __restrict__ x,
                                               const float* __restrict__ W,
                                               float* __restrict__ h1, int N) {
  __shared__ float sW[NFEAT * HID];     // 32 KB
  __shared__ float sx[256][XPAD];       // 20 KB
  float4* sW4 = (float4*)sW;
  const float4* W4 = (const float4*)W;
  for (int i = threadIdx.x; i < NFEAT * HID / 4; i += 256) sW4[i] = W4[i];

  const float4* x4 = (const float4*)x;
  const int row0 = blockIdx.x * 256;
  const int Nm1 = N - 1;
  const int jq = threadIdx.x & 3;
  const int rg = threadIdx.x >> 2;

  float4 acc[4];
#pragma unroll
  for (int m = 0; m < 4; m++) acc[m] = make_float4(0.f, 0.f, 0.f, 0.f);

  float4 ld[4];
  // preload chunk 0: 256 rows x 16 k = 1024 float4, 4 per thread
#pragma unroll
  for (int i = 0; i < 4; i++) {
    int f = threadIdx.x + (i << 8);
    int r = f >> 2, k4 = f & 3;
    int rr = row0 + r; if (rr > Nm1) rr = Nm1;
    ld[i] = x4[(size_t)rr * (NFEAT / 4) + k4];
  }

  for (int c = 0; c < NC; ++c) {
    // store staged chunk
#pragma unroll
    for (int i = 0; i < 4; i++) {
      int f = threadIdx.x + (i << 8);
      int r = f >> 2, k4 = f & 3;
      *(float4*)&sx[r][k4 << 2] = ld[i];
    }
    __syncthreads();
    // issue next chunk's global loads (hide latency under compute)
    if (c + 1 < NC) {
#pragma unroll
      for (int i = 0; i < 4; i++) {
        int f = threadIdx.x + (i << 8);
        int r = f >> 2, k4 = f & 3;
        int rr = row0 + r; if (rr > Nm1) rr = Nm1;
        ld[i] = x4[(size_t)rr * (NFEAT / 4) + (c + 1) * (KC / 4) + k4];
      }
    }
    // compute this chunk
#pragma unroll
    for (int q = 0; q < KC / 4; q++) {
      int k0 = c * KC + q * 4;
      float4 w0 = sW4[(k0 + 0) * 4 + jq];
      float4 w1 = sW4[(k0 + 1) * 4 + jq];
      float4 w2 = sW4[(k0 + 2) * 4 + jq];
      float4 w3 = sW4[(k0 + 3) * 4 + jq];
#pragma unroll
      for (int m = 0; m < 4; m++) {
        float4 xv = *(const float4*)&sx[rg + (m << 6)][q << 2];
        fma4(acc[m], xv.x, w0);
        fma4(acc[m], xv.y, w1);
        fma4(acc[m], xv.z, w2);
        fma4(acc[m], xv.w, w3);
      }
    }
    __syncthreads();
  }

#pragma unroll
  for (int m = 0; m < 4; m++) {
    int r = row0 + rg + (m << 6);
    if (r < N) *(float4*)&h1[(size_t)r * HID + (jq << 2)] = acc[m];
  }
}

// ---------------- aggregation 1: agg[dst] += h1[src]*norm ----------------
__global__ void k_agg1(const int* __restrict__ ei, const float* __restrict__ dinv,
                       const float* __restrict__ h1, float* __restrict__ agg, int E) {
  int e = blockIdx.x * 256 + threadIdx.x;
  if (e >= E) return;
  int s = ei[e];
  int d = ei[(size_t)E + e];
  float nrm = dinv[s] * dinv[d];
  const float4* hs = (const float4*)(h1 + (size_t)s * HID);
  float* ad = agg + (size_t)d * HID;
#pragma unroll
  for (int q = 0; q < 4; q++) {
    float4 v = hs[q];
    atomicAdd(ad + q * 4 + 0, v.x * nrm);
    atomicAdd(ad + q * 4 + 1, v.y * nrm);
    atomicAdd(ad + q * 4 + 2, v.z * nrm);
    atomicAdd(ad + q * 4 + 3, v.w * nrm);
  }
}

// ------- fuse: h1r = relu(agg + dinv^2*h1 + b1);  h2 = h1r @ W2  (16->2) -------
__global__ void k_fuse1(const float* __restrict__ agg, const float* __restrict__ h1,
                        const float* __restrict__ dinv, const float* __restrict__ b1,
                        const float* __restrict__ W2, float* __restrict__ h2, int N) {
  int i = blockIdx.x * 256 + threadIdx.x;
  if (i >= N) return;
  float di = dinv[i];
  float d2 = di * di;
  const float4* ag = (const float4*)(agg + (size_t)i * HID);
  const float4* hh = (const float4*)(h1 + (size_t)i * HID);
  float o0 = 0.f, o1 = 0.f;
#pragma unroll
  for (int q = 0; q < 4; q++) {
    float4 a = ag[q];
    float4 h = hh[q];
    float v;
    v = fmaxf(a.x + d2 * h.x + b1[q * 4 + 0], 0.f);
    o0 += v * W2[(q * 4 + 0) * 2 + 0]; o1 += v * W2[(q * 4 + 0) * 2 + 1];
    v = fmaxf(a.y + d2 * h.y + b1[q * 4 + 1], 0.f);
    o0 += v * W2[(q * 4 + 1) * 2 + 0]; o1 += v * W2[(q * 4 + 1) * 2 + 1];
    v = fmaxf(a.z + d2 * h.z + b1[q * 4 + 2], 0.f);
    o0 += v * W2[(q * 4 + 2) * 2 + 0]; o1 += v * W2[(q * 4 + 2) * 2 + 1];
    v = fmaxf(a.w + d2 * h.w + b1[q * 4 + 3], 0.f);
    o0 += v * W2[(q * 4 + 3) * 2 + 0]; o1 += v * W2[(q * 4 + 3) * 2 + 1];
  }
  *(float2*)&h2[(size_t)i * 2] = make_float2(o0, o1);
}

// ---------------- aggregation 2: out[dst] += h2[src]*norm ----------------
__global__ void k_agg2(const int* __restrict__ ei, const float* __restrict__ dinv,
                       const float* __restrict__ h2, float* __restrict__ out, int E) {
  int e = blockIdx.x * 256 + threadIdx.x;
  if (e >= E) return;
  int s = ei[e];
  int d = ei[(size_t)E + e];
  float nrm = dinv[s] * dinv[d];
  float2 v = *(const float2*)&h2[(size_t)s * 2];
  atomicAdd(&out[(size_t)d * 2 + 0], v.x * nrm);
  atomicAdd(&out[(size_t)d * 2 + 1], v.y * nrm);
}

// ---------------- epilogue: out += dinv^2*h2 + b2 ----------------
__global__ void k_post2(const float* __restrict__ dinv, const float* __restrict__ h2,
                        const float* __restrict__ b2, float* __restrict__ out, int N) {
  int i = blockIdx.x * 256 + threadIdx.x;
  if (i >= N) return;
  float d2 = dinv[i] * dinv[i];
  float2 h = *(const float2*)&h2[(size_t)i * 2];
  float2 o = *(float2*)&out[(size_t)i * 2];
  o.x += d2 * h.x + b2[0];
  o.y += d2 * h.y + b2[1];
  *(float2*)&out[(size_t)i * 2] = o;
}

extern "C" void kernel_launch(void* const* d_in, const int* in_sizes, int n_in,
                              void* d_out, int out_size, void* d_ws, size_t ws_size,
                              hipStream_t stream) {
  const float* x = (const float*)d_in[0];
  const int* ei = (const int*)d_in[1];   // harness delivers integer inputs as int32
  const float* W1 = (const float*)d_in[2];
  const float* b1 = (const float*)d_in[3];
  const float* W2 = (const float*)d_in[4];
  const float* b2 = (const float*)d_in[5];
  float* out = (float*)d_out;
  const int N = in_sizes[0] / NFEAT;
  const int E = in_sizes[1] / 2;

  // workspace layout (floats): dinv[N] | h1[N*16] | agg[N*16] | h2[N*2]  (~14 MB)
  float* ws = (float*)d_ws;
  float* dinv = ws;                       // deg, then in-place rsqrt
  float* h1 = dinv + N;
  float* agg = h1 + (size_t)N * HID;
  float* h2 = agg + (size_t)N * HID;

  (void)hipMemsetAsync(agg, 0, (size_t)N * HID * sizeof(float), stream);
  (void)hipMemsetAsync(d_out, 0, (size_t)out_size * sizeof(float), stream);

  const int nb = (N + 255) / 256;
  const int eb = (E + 255) / 256;

  k_deg_init<<<nb, 256, 0, stream>>>(dinv, N);
  k_deg_count<<<eb, 256, 0, stream>>>(ei, dinv, E);
  k_dinv<<<nb, 256, 0, stream>>>(dinv, N);
  k_gemm1<<<nb, 256, 0, stream>>>(x, W1, h1, N);
  k_agg1<<<eb, 256, 0, stream>>>(ei, dinv, h1, agg, E);
  k_fuse1<<<nb, 256, 0, stream>>>(agg, h1, dinv, b1, W2, h2, N);
  k_agg2<<<eb, 256, 0, stream>>>(ei, dinv, h2, out, E);
  k_post2<<<nb, 256, 0, stream>>>(dinv, h2, b2, out, N);
}

// Round 4
// 640.713 us; speedup vs baseline: 5.0295x; 5.0295x over previous
//
#include <hip/hip_runtime.h>

#define NFEAT 512
#define HID 16

// ================= CSR build =================

__global__ void k_deg_count(const int* __restrict__ ei, int* __restrict__ deg, int E) {
  int e = blockIdx.x * 256 + threadIdx.x;
  if (e < E) atomicAdd(&deg[ei[(size_t)E + e]], 1);
}

// per-block (1024 elems) inclusive scan
__global__ __launch_bounds__(256) void k_scan1(const int* __restrict__ deg,
                                               int* __restrict__ incl,
                                               int* __restrict__ bsum, int n) {
  __shared__ int sm[256];
  int t = threadIdx.x;
  int base = blockIdx.x * 1024 + t * 4;
  int v0 = 0, v1 = 0, v2 = 0, v3 = 0;
  if (base + 3 < n) {
    int4 q = *(const int4*)&deg[base];
    v0 = q.x; v1 = q.y; v2 = q.z; v3 = q.w;
  } else {
    if (base < n) v0 = deg[base];
    if (base + 1 < n) v1 = deg[base + 1];
    if (base + 2 < n) v2 = deg[base + 2];
    if (base + 3 < n) v3 = deg[base + 3];
  }
  int p0 = v0, p1 = p0 + v1, p2 = p1 + v2, p3 = p2 + v3;
  sm[t] = p3;
  __syncthreads();
  for (int off = 1; off < 256; off <<= 1) {
    int x = (t >= off) ? sm[t - off] : 0;
    __syncthreads();
    sm[t] += x;
    __syncthreads();
  }
  int excl = sm[t] - p3;
  if (base < n) incl[base] = excl + p0;
  if (base + 1 < n) incl[base + 1] = excl + p1;
  if (base + 2 < n) incl[base + 2] = excl + p2;
  if (base + 3 < n) incl[base + 3] = excl + p3;
  if (t == 255) bsum[blockIdx.x] = sm[t];
}

// serial exclusive scan of block sums (nb ~ 98, trivial)
__global__ void k_scan2(int* __restrict__ bsum, int nb) {
  if (threadIdx.x == 0 && blockIdx.x == 0) {
    int run = 0;
    for (int b = 0; b < nb; ++b) {
      int v = bsum[b];
      bsum[b] = run;
      run += v;
    }
  }
}

// rowptr / cursor / dinv
__global__ void k_scan3(const int* __restrict__ deg, const int* __restrict__ incl,
                        const int* __restrict__ bsum, int* __restrict__ rowptr,
                        int* __restrict__ cursor, float* __restrict__ dinv, int n) {
  int i = blockIdx.x * 256 + threadIdx.x;
  if (i >= n) return;
  int inc = incl[i] + bsum[i >> 10];
  rowptr[i + 1] = inc;
  cursor[i] = inc - deg[i];
  dinv[i] = rsqrtf((float)deg[i] + 1.0f);  // +1 self loop
  if (i == 0) rowptr[0] = 0;
}

__global__ void k_scatter(const int* __restrict__ ei, int* __restrict__ cursor,
                          int* __restrict__ csr_src, int E) {
  int e = blockIdx.x * 256 + threadIdx.x;
  if (e >= E) return;
  int s = ei[e];
  int d = ei[(size_t)E + e];
  int pos = atomicAdd(&cursor[d], 1);
  csr_src[pos] = s;
}

// ================= GEMM1: h1s = (x @ W1) * dinv[row] =================
#define KC 16
#define NC (NFEAT / KC)
#define XPAD 20

__device__ __forceinline__ void fma4(float4& a, float s, const float4& b) {
  a.x += s * b.x;
  a.y += s * b.y;
  a.z += s * b.z;
  a.w += s * b.w;
}

__global__ __launch_bounds__(256) void k_gemm1(const float* __restrict__ x,
                                               const float* __restrict__ W,
                                               const float* __restrict__ dinv,
                                               float* __restrict__ h1s, int N) {
  __shared__ float sW[NFEAT * HID];  // 32 KB
  __shared__ float sx[256][XPAD];    // 20 KB
  float4* sW4 = (float4*)sW;
  const float4* W4 = (const float4*)W;
  for (int i = threadIdx.x; i < NFEAT * HID / 4; i += 256) sW4[i] = W4[i];

  const float4* x4 = (const float4*)x;
  const int row0 = blockIdx.x * 256;
  const int Nm1 = N - 1;
  const int jq = threadIdx.x & 3;
  const int rg = threadIdx.x >> 2;

  float4 acc[4];
#pragma unroll
  for (int m = 0; m < 4; m++) acc[m] = make_float4(0.f, 0.f, 0.f, 0.f);

  float4 ld[4];
#pragma unroll
  for (int i = 0; i < 4; i++) {
    int f = threadIdx.x + (i << 8);
    int r = f >> 2, k4 = f & 3;
    int rr = row0 + r; if (rr > Nm1) rr = Nm1;
    ld[i] = x4[(size_t)rr * (NFEAT / 4) + k4];
  }

  for (int c = 0; c < NC; ++c) {
#pragma unroll
    for (int i = 0; i < 4; i++) {
      int f = threadIdx.x + (i << 8);
      int r = f >> 2, k4 = f & 3;
      *(float4*)&sx[r][k4 << 2] = ld[i];
    }
    __syncthreads();
    if (c + 1 < NC) {
#pragma unroll
      for (int i = 0; i < 4; i++) {
        int f = threadIdx.x + (i << 8);
        int r = f >> 2, k4 = f & 3;
        int rr = row0 + r; if (rr > Nm1) rr = Nm1;
        ld[i] = x4[(size_t)rr * (NFEAT / 4) + (c + 1) * (KC / 4) + k4];
      }
    }
#pragma unroll
    for (int q = 0; q < KC / 4; q++) {
      int k0 = c * KC + q * 4;
      float4 w0 = sW4[(k0 + 0) * 4 + jq];
      float4 w1 = sW4[(k0 + 1) * 4 + jq];
      float4 w2 = sW4[(k0 + 2) * 4 + jq];
      float4 w3 = sW4[(k0 + 3) * 4 + jq];
#pragma unroll
      for (int m = 0; m < 4; m++) {
        float4 xv = *(const float4*)&sx[rg + (m << 6)][q << 2];
        fma4(acc[m], xv.x, w0);
        fma4(acc[m], xv.y, w1);
        fma4(acc[m], xv.z, w2);
        fma4(acc[m], xv.w, w3);
      }
    }
    __syncthreads();
  }

#pragma unroll
  for (int m = 0; m < 4; m++) {
    int r = row0 + rg + (m << 6);
    if (r < N) {
      float di = dinv[r];
      acc[m].x *= di; acc[m].y *= di; acc[m].z *= di; acc[m].w *= di;
      *(float4*)&h1s[(size_t)r * HID + (jq << 2)] = acc[m];
    }
  }
}

// ===== layer1 aggregation + relu + W2, fused.  16 lanes per node. =====
// h2s[node] = dinv[node] * ( relu( dinv[node]*(h1s[node] + sum_src h1s[src]) + b1 ) @ W2 )
__global__ __launch_bounds__(256) void k_agg1f(const int* __restrict__ rowptr,
                                               const int* __restrict__ csr_src,
                                               const float* __restrict__ h1s,
                                               const float* __restrict__ dinv,
                                               const float* __restrict__ b1,
                                               const float* __restrict__ W2,
                                               float* __restrict__ h2s, int N) {
  const int f = threadIdx.x & 15;
  const int node = blockIdx.x * 16 + (threadIdx.x >> 4);
  if (node >= N) return;
  const int beg = rowptr[node];
  const int end = rowptr[node + 1];
  float acc = h1s[(size_t)node * HID + f];  // self loop term (pre-scaled by dinv[node])
  for (int j = beg; j < end; ++j) {
    int s = csr_src[j];                      // broadcast within the 16-lane group
    acc += h1s[(size_t)s * HID + f];
  }
  float di = dinv[node];
  float v = fmaxf(acc * di + b1[f], 0.f);
  float o0 = v * W2[f * 2 + 0];
  float o1 = v * W2[f * 2 + 1];
#pragma unroll
  for (int d = 1; d < 16; d <<= 1) {
    o0 += __shfl_xor(o0, d);
    o1 += __shfl_xor(o1, d);
  }
  if (f == 0) *(float2*)&h2s[(size_t)node * 2] = make_float2(o0 * di, o1 * di);
}

// ===== layer2 aggregation + bias, fused.  thread per node. =====
// out[node] = dinv[node]*(h2s[node] + sum_src h2s[src]) + b2
__global__ __launch_bounds__(256) void k_agg2f(const int* __restrict__ rowptr,
                                               const int* __restrict__ csr_src,
                                               const float* __restrict__ h2s,
                                               const float* __restrict__ dinv,
                                               const float* __restrict__ b2,
                                               float* __restrict__ out, int N) {
  int i = blockIdx.x * 256 + threadIdx.x;
  if (i >= N) return;
  int beg = rowptr[i], end = rowptr[i + 1];
  float2 o = *(const float2*)&h2s[(size_t)i * 2];  // self loop
  for (int j = beg; j < end; ++j) {
    int s = csr_src[j];
    float2 v = *(const float2*)&h2s[(size_t)s * 2];
    o.x += v.x;
    o.y += v.y;
  }
  float di = dinv[i];
  o.x = o.x * di + b2[0];
  o.y = o.y * di + b2[1];
  *(float2*)&out[(size_t)i * 2] = o;
}

// ================= launch =================
extern "C" void kernel_launch(void* const* d_in, const int* in_sizes, int n_in,
                              void* d_out, int out_size, void* d_ws, size_t ws_size,
                              hipStream_t stream) {
  const float* x = (const float*)d_in[0];
  const int* ei = (const int*)d_in[1];  // harness delivers integer inputs as int32
  const float* W1 = (const float*)d_in[2];
  const float* b1 = (const float*)d_in[3];
  const float* W2 = (const float*)d_in[4];
  const float* b2 = (const float*)d_in[5];
  float* out = (float*)d_out;
  const int N = in_sizes[0] / NFEAT;
  const int E = in_sizes[1] / 2;

  // workspace: deg[N] incl[N] bsum[256] rowptr[N+1] cursor[N] csr_src[E] (ints)
  //            dinv[N] h1s[16N] h2s[2N] (floats)   total ~21.6 MB
  char* p = (char*)d_ws;
  int* deg = (int*)p;            p += (size_t)N * 4;
  int* incl = (int*)p;           p += (size_t)N * 4;
  int* bsum = (int*)p;           p += 256 * 4;
  int* rowptr = (int*)p;         p += (size_t)(N + 1) * 4;
  int* cursor = (int*)p;         p += (size_t)N * 4;
  int* csr_src = (int*)p;        p += (size_t)E * 4;
  float* dinv = (float*)p;       p += (size_t)N * 4;
  float* h1s = (float*)p;        p += (size_t)N * HID * 4;
  float* h2s = (float*)p;        p += (size_t)N * 2 * 4;

  const int nb = (N + 255) / 256;
  const int eb = (E + 255) / 256;
  const int sb = (N + 1023) / 1024;

  (void)hipMemsetAsync(deg, 0, (size_t)N * sizeof(int), stream);
  k_deg_count<<<eb, 256, 0, stream>>>(ei, deg, E);
  k_scan1<<<sb, 256, 0, stream>>>(deg, incl, bsum, N);
  k_scan2<<<1, 64, 0, stream>>>(bsum, sb);
  k_scan3<<<nb, 256, 0, stream>>>(deg, incl, bsum, rowptr, cursor, dinv, N);
  k_scatter<<<eb, 256, 0, stream>>>(ei, cursor, csr_src, E);
  k_gemm1<<<nb, 256, 0, stream>>>(x, W1, dinv, h1s, N);
  k_agg1f<<<(N + 15) / 16, 256, 0, stream>>>(rowptr, csr_src, h1s, dinv, b1, W2, h2s, N);
  k_agg2f<<<nb, 256, 0, stream>>>(rowptr, csr_src, h2s, dinv, b2, out, N);
}